// Round 7
// baseline (480.179 us; speedup 1.0000x reference)
//
#include <hip/hip_runtime.h>
#include <stdint.h>

// Problem constants (from reference)
#define N_CLASSES  10
#define N_TREES    4000
#define DEPTH      6
#define N_INTERNAL 63
#define N_FEATURES 128
#define BATCH      32768
#define LR         0.1f

// Kernel config: one tree per wave (64 lanes = 64 samples), ILP=4 trees/wave.
#define BLOCK       256
#define SAMPLES_PB  64
#define TSPLIT      2
#define SLOTS_PB    (N_TREES / TSPLIT)      // 2000 class-grouped slots per block
#define ILP         4                       // trees in flight per wave
#define T_TILE      16                      // 4 waves * ILP trees per LDS tile (8 KB)
#define N_TILES     (SLOTS_PB / T_TILE)     // 125
#define TILES_PER_CLASS 25                  // 400 / 16
#define CLASSES_PB  (N_CLASSES / TSPLIT)    // 5
#define SUMS_STRIDE 11

// ws: [0, 2.048MB) nodes by slot, interleaved int2 (feat, thr_bits), 64 per tree;
//     [2.048MB, 3.072MB) leaves (64 f32 per tree). slot = (t%10)*400 + t/10.
#define WS_NODES_BYTES  ((size_t)N_TREES * 64 * 8)
#define WS_LEAVES_BYTES ((size_t)N_TREES * 64 * 4)

__global__ void pack_kernel(const int* __restrict__ features,
                            const float* __restrict__ thresholds,
                            const float* __restrict__ leaves,
                            int2* __restrict__ pn, float* __restrict__ pl) {
    int i = blockIdx.x * blockDim.x + threadIdx.x;   // over N_TREES*64
    int t = i >> 6, n = i & 63;
    if (t < N_TREES) {
        int slot = (t % N_CLASSES) * (N_TREES / N_CLASSES) + (t / N_CLASSES);
        if (n < N_INTERNAL)
            pn[slot * 64 + n] = make_int2(features[t * N_INTERNAL + n],
                                          __float_as_int(thresholds[t * N_INTERNAL + n]));
        pl[slot * 64 + n] = leaves[t * 64 + n];
    }
}

__global__ void out_init_kernel(const float* __restrict__ init_out,
                                float* __restrict__ out) {
    int i = blockIdx.x * blockDim.x + threadIdx.x;
    if (i < BATCH * N_CLASSES) {
        int s = i / N_CLASSES;
        out[i] = init_out[i - s * N_CLASSES];
    }
}

__device__ __forceinline__ void load_lds_16(const void* g, void* l) {
    const auto* g1 = reinterpret_cast<const __attribute__((address_space(1))) uint32_t*>(
        reinterpret_cast<uintptr_t>(g));
    auto* l3 = reinterpret_cast<__attribute__((address_space(3))) uint32_t*>(
        reinterpret_cast<uintptr_t>(l));
    __builtin_amdgcn_global_load_lds(g1, l3, 16, 0, 0);
}

__global__ __launch_bounds__(BLOCK, 2) void gbt_eval(
    const float* __restrict__ x,
    const int2*  __restrict__ pnodes,   // [N_TREES][64] int2, class-grouped slots
    const float* __restrict__ pleaves,  // [N_TREES][64], class-grouped slots
    float*       __restrict__ out)      // [BATCH][10], pre-init to init_out
{
    __shared__ float xs[N_FEATURES * SAMPLES_PB];   // 32 KB, transposed [f][s]
    __shared__ int2  nbuf[2][T_TILE * 64];          // 2 x 8 KB node tiles
    __shared__ float sums[SAMPLES_PB * SUMS_STRIDE];// 2.8 KB
    __shared__ float pad_2blk[1024];                // 4 KB: forces 2 blocks/CU
                                                    // (grid 1024 = 2 exact rounds)
    const int tid = threadIdx.x;
    if (tid >= BLOCK) pad_2blk[0] = 0.f;            // keep pad alive (unreachable)

    const int sample0 = blockIdx.x * SAMPLES_PB;
    const int slot0   = blockIdx.y * SLOTS_PB;
    const int cls0    = blockIdx.y * CLASSES_PB;
    const int lane    = tid & 63;
    const int wvu     = __builtin_amdgcn_readfirstlane(tid >> 6);  // uniform wave id

    // Stage x transposed: xs[f*64 + s]; hot-loop bank = s%32 -> 2-way = free.
    {
        const float4* xg = (const float4*)(x + (size_t)sample0 * N_FEATURES);
        for (int e = tid; e < SAMPLES_PB * (N_FEATURES / 4); e += BLOCK) {
            int s = e >> 5, f4 = e & 31;
            float4 v = xg[e];
            int f = f4 << 2;
            xs[(f + 0) * SAMPLES_PB + s] = v.x;
            xs[(f + 1) * SAMPLES_PB + s] = v.y;
            xs[(f + 2) * SAMPLES_PB + s] = v.z;
            xs[(f + 3) * SAMPLES_PB + s] = v.w;
        }
    }
    for (int i = tid; i < SAMPLES_PB * SUMS_STRIDE; i += BLOCK) sums[i] = 0.f;

    // Stage one 8 KB tile: each wave DMAs its own 2 KB (2 x 1 KB instrs).
    auto stage = [&](int tile, int b) {
        const char* g = (const char*)(pnodes + (size_t)(slot0 + tile * T_TILE) * 64);
        char* l = (char*)&nbuf[b][0];
        #pragma unroll
        for (int q = 0; q < 2; ++q) {
            int off = wvu * 2048 + q * 1024;
            load_lds_16(g + off + lane * 16, l + off);
        }
    };

    stage(0, 0);
    __syncthreads();

    int cur = 0;
    for (int c5 = 0; c5 < CLASSES_PB; ++c5) {
        float acc = 0.f;                 // one class per 25-tile span
        for (int t25 = 0; t25 < TILES_PER_CLASS; ++t25) {
            const int tile = c5 * TILES_PER_CLASS + t25;
            if (tile + 1 < N_TILES) stage(tile + 1, cur ^ 1);

            const int slotw = slot0 + tile * T_TILE + wvu * ILP;  // uniform

            // Levels 0-2 node data (nodes 0..6) via wave-uniform loads ->
            // s_load on the SMEM pipe; selection by v_cndmask. Walk-independent,
            // so no dependent-latency chain (the R6 trap).
            int2 ns[ILP][7];
            #pragma unroll
            for (int u = 0; u < ILP; ++u) {
                const int2* tb = pnodes + (size_t)(slotw + u) * 64;
                #pragma unroll
                for (int k = 0; k < 7; ++k) ns[u][k] = tb[k];
            }

            float xv[ILP]; bool b0[ILP], b1[ILP], b2[ILP]; int o[ILP];
            // L0
            #pragma unroll
            for (int u = 0; u < ILP; ++u) xv[u] = xs[ns[u][0].x * SAMPLES_PB + lane];
            #pragma unroll
            for (int u = 0; u < ILP; ++u) b0[u] = xv[u] > __int_as_float(ns[u][0].y);
            // L1
            #pragma unroll
            for (int u = 0; u < ILP; ++u) {
                int f = b0[u] ? ns[u][2].x : ns[u][1].x;
                xv[u] = xs[f * SAMPLES_PB + lane];
            }
            #pragma unroll
            for (int u = 0; u < ILP; ++u) {
                float t = __int_as_float(b0[u] ? ns[u][2].y : ns[u][1].y);
                b1[u] = xv[u] > t;
            }
            // L2
            #pragma unroll
            for (int u = 0; u < ILP; ++u) {
                int f = b0[u] ? (b1[u] ? ns[u][6].x : ns[u][5].x)
                              : (b1[u] ? ns[u][4].x : ns[u][3].x);
                xv[u] = xs[f * SAMPLES_PB + lane];
            }
            #pragma unroll
            for (int u = 0; u < ILP; ++u) {
                float t = __int_as_float(b0[u] ? (b1[u] ? ns[u][6].y : ns[u][5].y)
                                               : (b1[u] ? ns[u][4].y : ns[u][3].y));
                b2[u] = xv[u] > t;
                o[u] = 7 + 4 * (int)b0[u] + 2 * (int)b1[u] + (int)b2[u];
            }
            // L3-L5 from the LDS tile: ds_read_b64 (interleaved int2)
            #pragma unroll
            for (int d = 3; d < 6; ++d) {
                int2 a[ILP];
                #pragma unroll
                for (int u = 0; u < ILP; ++u)
                    a[u] = nbuf[cur][(wvu * ILP + u) * 64 + o[u]];
                #pragma unroll
                for (int u = 0; u < ILP; ++u)
                    xv[u] = xs[a[u].x * SAMPLES_PB + lane];
                #pragma unroll
                for (int u = 0; u < ILP; ++u)
                    o[u] = 2 * o[u] + 1 + (xv[u] > __int_as_float(a[u].y) ? 1 : 0);
            }
            // Leaves from global (VMEM, L2-resident)
            #pragma unroll
            for (int u = 0; u < ILP; ++u)
                acc += pleaves[(size_t)(slotw + u) * 64 + (o[u] - N_INTERNAL)];

            __syncthreads();   // nbuf[cur] reads done; prefetch DMA drained
            cur ^= 1;
        }
        atomicAdd(&sums[lane * SUMS_STRIDE + cls0 + c5], acc);
    }
    __syncthreads();

    for (int e = tid; e < SAMPLES_PB * N_CLASSES; e += BLOCK) {
        int s = e / N_CLASSES, k = e - s * N_CLASSES;
        atomicAdd(&out[(size_t)(sample0 + s) * N_CLASSES + k],
                  LR * sums[s * SUMS_STRIDE + k]);
    }
}

// Fallback (ws too small): R3-style direct-global gather.
__global__ __launch_bounds__(BLOCK, 8) void gbt_eval_global(
    const float* __restrict__ x,
    const int*   __restrict__ features,
    const float* __restrict__ thresholds,
    const float* __restrict__ leaf_values,
    float*       __restrict__ out)
{
    __shared__ float xs[N_FEATURES * 32];
    __shared__ float sums[32 * N_CLASSES];
    const int tid = threadIdx.x;
    const int sample0 = blockIdx.x * 32;
    {
        const float4* xg = (const float4*)(x + (size_t)sample0 * N_FEATURES);
        for (int e = tid; e < 32 * (N_FEATURES / 4); e += BLOCK) {
            int s = e >> 5, f4 = e & 31;
            float4 v = xg[e];
            int f = f4 << 2;
            xs[(f + 0) * 32 + s] = v.x;
            xs[(f + 1) * 32 + s] = v.y;
            xs[(f + 2) * 32 + s] = v.z;
            xs[(f + 3) * 32 + s] = v.w;
        }
    }
    for (int i = tid; i < 32 * N_CLASSES; i += BLOCK) sums[i] = 0.f;
    __syncthreads();
    const int sLocal = tid & 31;
    const int j = tid >> 5;
    const int TPT = N_TREES / (8 * TSPLIT);
    const int t0 = (blockIdx.y * 8 + j) * TPT;
    float acc[N_CLASSES];
    #pragma unroll
    for (int k = 0; k < N_CLASSES; ++k) acc[k] = 0.f;
    for (int i = 0; i < TPT; i += N_CLASSES) {
        const int tt = t0 + i;
        int idx[N_CLASSES];
        #pragma unroll
        for (int u = 0; u < N_CLASSES; ++u) idx[u] = 0;
        #pragma unroll
        for (int d = 0; d < DEPTH; ++d) {
            #pragma unroll
            for (int u = 0; u < N_CLASSES; ++u) {
                int base = (tt + u) * N_INTERNAL + idx[u];
                float xv = xs[features[base] * 32 + sLocal];
                idx[u] = 2 * idx[u] + 1 + (xv > thresholds[base] ? 1 : 0);
            }
        }
        #pragma unroll
        for (int u = 0; u < N_CLASSES; ++u)
            acc[u] += leaf_values[(size_t)(tt + u) * 64 + idx[u] - N_INTERNAL];
    }
    #pragma unroll
    for (int k = 0; k < N_CLASSES; ++k)
        atomicAdd(&sums[sLocal * N_CLASSES + k], acc[k]);
    __syncthreads();
    for (int e = tid; e < 32 * N_CLASSES; e += BLOCK) {
        int s = e / N_CLASSES, k = e - s * N_CLASSES;
        atomicAdd(&out[(size_t)(sample0 + s) * N_CLASSES + k], LR * sums[e]);
    }
}

extern "C" void kernel_launch(void* const* d_in, const int* in_sizes, int n_in,
                              void* d_out, int out_size, void* d_ws, size_t ws_size,
                              hipStream_t stream) {
    const float* x          = (const float*)d_in[0];
    const int*   features   = (const int*)d_in[1];
    const float* thresholds = (const float*)d_in[2];
    const float* leafvals   = (const float*)d_in[3];
    const float* init_out   = (const float*)d_in[4];
    float*       out        = (float*)d_out;

    {
        int n = BATCH * N_CLASSES;
        out_init_kernel<<<(n + 255) / 256, 256, 0, stream>>>(init_out, out);
    }

    if (ws_size >= WS_NODES_BYTES + WS_LEAVES_BYTES) {
        int2*  pn = (int2*)d_ws;
        float* pl = (float*)((char*)d_ws + WS_NODES_BYTES);
        int n = N_TREES * 64;
        pack_kernel<<<(n + 255) / 256, 256, 0, stream>>>(features, thresholds,
                                                         leafvals, pn, pl);
        dim3 grid(BATCH / SAMPLES_PB, TSPLIT);   // 512 x 2 = 1024 blocks
        gbt_eval<<<grid, BLOCK, 0, stream>>>(x, pn, pl, out);
    } else {
        dim3 grid(BATCH / 32, TSPLIT);
        gbt_eval_global<<<grid, BLOCK, 0, stream>>>(x, features, thresholds,
                                                    leafvals, out);
    }
}

// Round 8
// 328.904 us; speedup vs baseline: 1.4599x; 1.4599x over previous
//
#include <hip/hip_runtime.h>
#include <stdint.h>

// Problem constants (from reference)
#define N_CLASSES  10
#define N_TREES    4000
#define DEPTH      6
#define N_INTERNAL 63
#define N_FEATURES 128
#define BATCH      32768
#define LR         0.1f

// Kernel config (R5 skeleton: 32 samples/block, half-wave = 32 lanes walk one
// tree; 16 waves/CU; all node traffic on the LDS pipe).
#define BLOCK       256
#define SAMPLES_PB  32
#define TSPLIT      2                       // tree split across blockIdx.y
#define SLOTS_PB    (N_TREES / TSPLIT)      // 2000 class-grouped slots per block
#define T_TILE      16                      // trees per LDS tile (8 KB int2 nodes)
#define N_TILES     (SLOTS_PB / T_TILE)     // 125
#define TILES_PER_CLASS 25                  // 400 trees/class / 16
#define SUMS_STRIDE 11

// ws: [0, 2.048MB) nodes by slot, INTERLEAVED int2 (feat, thr_bits), 64/tree;
//     [2.048MB, 3.072MB) leaves (64 f32/tree). slot = (t%10)*400 + t/10.
#define WS_NODES_BYTES  ((size_t)N_TREES * 64 * 8)
#define WS_LEAVES_BYTES ((size_t)N_TREES * 64 * 4)

__global__ void pack_kernel(const int* __restrict__ features,
                            const float* __restrict__ thresholds,
                            const float* __restrict__ leaves,
                            int2* __restrict__ pn, float* __restrict__ pl) {
    int i = blockIdx.x * blockDim.x + threadIdx.x;   // over N_TREES*64
    int t = i >> 6, n = i & 63;
    if (t < N_TREES) {
        int slot = (t % N_CLASSES) * (N_TREES / N_CLASSES) + (t / N_CLASSES);
        if (n < N_INTERNAL)
            pn[slot * 64 + n] = make_int2(features[t * N_INTERNAL + n],
                                          __float_as_int(thresholds[t * N_INTERNAL + n]));
        pl[slot * 64 + n] = leaves[t * 64 + n];
    }
}

__global__ void out_init_kernel(const float* __restrict__ init_out,
                                float* __restrict__ out) {
    int i = blockIdx.x * blockDim.x + threadIdx.x;
    if (i < BATCH * N_CLASSES) {
        int s = i / N_CLASSES;
        out[i] = init_out[i - s * N_CLASSES];
    }
}

// CK-style addrspace casts for global_load_lds (proven R5).
__device__ __forceinline__ void load_lds_16(const void* g, void* l) {
    const auto* g1 = reinterpret_cast<const __attribute__((address_space(1))) uint32_t*>(
        reinterpret_cast<uintptr_t>(g));
    auto* l3 = reinterpret_cast<__attribute__((address_space(3))) uint32_t*>(
        reinterpret_cast<uintptr_t>(l));
    __builtin_amdgcn_global_load_lds(g1, l3, 16, 0, 0);
}

__global__ __launch_bounds__(BLOCK, 4) void gbt_eval(
    const float* __restrict__ x,
    const int2*  __restrict__ pnodes,   // [N_TREES][64] int2, class-grouped slots
    const float* __restrict__ pleaves,  // [N_TREES][64], class-grouped slots
    float*       __restrict__ out)      // [BATCH][10], pre-init to init_out
{
    __shared__ float xs[N_FEATURES * SAMPLES_PB];       // 16 KB, transposed
    __shared__ int2  nbuf[2][T_TILE * 64];              // 2 x 8 KB node tiles
    __shared__ float sums[SAMPLES_PB * SUMS_STRIDE];    // 1.4 KB

    const int tid = threadIdx.x;
    const int sample0 = blockIdx.x * SAMPLES_PB;
    const int slot0   = blockIdx.y * SLOTS_PB;
    const int cls0    = blockIdx.y * (N_CLASSES / TSPLIT);  // 5 classes per block

    // Stage x transposed: xs[f*32 + s]; hot-loop bank = s%32, conflict-free.
    {
        const float4* xg = (const float4*)(x + (size_t)sample0 * N_FEATURES);
        for (int e = tid; e < SAMPLES_PB * (N_FEATURES / 4); e += BLOCK) {
            int s = e >> 5, f4 = e & 31;
            float4 v = xg[e];
            int f = f4 << 2;
            xs[(f + 0) * SAMPLES_PB + s] = v.x;
            xs[(f + 1) * SAMPLES_PB + s] = v.y;
            xs[(f + 2) * SAMPLES_PB + s] = v.z;
            xs[(f + 3) * SAMPLES_PB + s] = v.w;
        }
    }
    for (int i = tid; i < SAMPLES_PB * SUMS_STRIDE; i += BLOCK) sums[i] = 0.f;

    const int lane = tid & 63;
    const int wv   = tid >> 6;          // wave id 0..3

    // Stage one 8 KB int2 node tile: 8 chunks of 1 KB; wave wv DMAs 2 chunks.
    auto stage = [&](int tile, int b) {
        const char* g = (const char*)(pnodes + (size_t)(slot0 + tile * T_TILE) * 64);
        char* lbase = (char*)&nbuf[b][0];
        #pragma unroll
        for (int q = 0; q < 2; ++q) {
            int k = wv * 2 + q;
            load_lds_16(g + k * 1024 + lane * 16, lbase + k * 1024);
        }
    };

    stage(0, 0);
    __syncthreads();   // tile 0 + xs visible

    const int sLocal = tid & (SAMPLES_PB - 1);
    const int j      = tid >> 5;        // 0..7 half-wave chunks; trees 2j, 2j+1

    int cur = 0;
    for (int c5 = 0; c5 < N_CLASSES / TSPLIT; ++c5) {
        float acc = 0.f;                // tile is single-class (class-grouped slots)
        for (int t25 = 0; t25 < TILES_PER_CLASS; ++t25) {
            const int tile = c5 * TILES_PER_CLASS + t25;
            if (tile + 1 < N_TILES) stage(tile + 1, cur ^ 1);

            const int2* nb0 = &nbuf[cur][(j * 2 + 0) * 64];
            const int2* nb1 = &nbuf[cur][(j * 2 + 1) * 64];
            int o0 = 0, o1 = 0;
            #pragma unroll
            for (int d = 0; d < DEPTH; ++d) {
                int2 a = nb0[o0];           // ds_read_b64 (interleaved f,thr)
                int2 b = nb1[o1];           // ds_read_b64
                float x0 = xs[a.x * SAMPLES_PB + sLocal];
                float x1 = xs[b.x * SAMPLES_PB + sLocal];
                o0 = 2 * o0 + 1 + (x0 > __int_as_float(a.y) ? 1 : 0);
                o1 = 2 * o1 + 1 + (x1 > __int_as_float(b.y) ? 1 : 0);
            }
            const size_t slotA = (size_t)(slot0 + tile * T_TILE + j * 2);
            acc += pleaves[slotA * 64       + (o0 - N_INTERNAL)];   // L2-resident
            acc += pleaves[(slotA + 1) * 64 + (o1 - N_INTERNAL)];

            __syncthreads();   // nbuf[cur] reads done; prefetch DMA long landed
            cur ^= 1;
        }
        atomicAdd(&sums[sLocal * SUMS_STRIDE + cls0 + c5], acc);
    }
    __syncthreads();

    for (int e = tid; e < SAMPLES_PB * N_CLASSES; e += BLOCK) {
        int s = e / N_CLASSES, k = e - s * N_CLASSES;
        atomicAdd(&out[(size_t)(sample0 + s) * N_CLASSES + k],
                  LR * sums[s * SUMS_STRIDE + k]);
    }
}

// Fallback (ws too small): R3-style direct-global gather.
__global__ __launch_bounds__(BLOCK, 8) void gbt_eval_global(
    const float* __restrict__ x,
    const int*   __restrict__ features,
    const float* __restrict__ thresholds,
    const float* __restrict__ leaf_values,
    float*       __restrict__ out)
{
    __shared__ float xs[N_FEATURES * SAMPLES_PB];
    __shared__ float sums[SAMPLES_PB * N_CLASSES];
    const int tid = threadIdx.x;
    const int sample0 = blockIdx.x * SAMPLES_PB;
    {
        const float4* xg = (const float4*)(x + (size_t)sample0 * N_FEATURES);
        for (int e = tid; e < SAMPLES_PB * (N_FEATURES / 4); e += BLOCK) {
            int s = e >> 5, f4 = e & 31;
            float4 v = xg[e];
            int f = f4 << 2;
            xs[(f + 0) * SAMPLES_PB + s] = v.x;
            xs[(f + 1) * SAMPLES_PB + s] = v.y;
            xs[(f + 2) * SAMPLES_PB + s] = v.z;
            xs[(f + 3) * SAMPLES_PB + s] = v.w;
        }
    }
    for (int i = tid; i < SAMPLES_PB * N_CLASSES; i += BLOCK) sums[i] = 0.f;
    __syncthreads();
    const int sLocal = tid & (SAMPLES_PB - 1);
    const int j = tid >> 5;
    const int TPT = N_TREES / (8 * TSPLIT);
    const int t0 = (blockIdx.y * 8 + j) * TPT;
    float acc[N_CLASSES];
    #pragma unroll
    for (int k = 0; k < N_CLASSES; ++k) acc[k] = 0.f;
    for (int i = 0; i < TPT; i += N_CLASSES) {
        const int tt = t0 + i;
        int idx[N_CLASSES];
        #pragma unroll
        for (int u = 0; u < N_CLASSES; ++u) idx[u] = 0;
        #pragma unroll
        for (int d = 0; d < DEPTH; ++d) {
            #pragma unroll
            for (int u = 0; u < N_CLASSES; ++u) {
                int base = (tt + u) * N_INTERNAL + idx[u];
                float xv = xs[features[base] * SAMPLES_PB + sLocal];
                idx[u] = 2 * idx[u] + 1 + (xv > thresholds[base] ? 1 : 0);
            }
        }
        #pragma unroll
        for (int u = 0; u < N_CLASSES; ++u)
            acc[u] += leaf_values[(size_t)(tt + u) * 64 + idx[u] - N_INTERNAL];
    }
    #pragma unroll
    for (int k = 0; k < N_CLASSES; ++k)
        atomicAdd(&sums[sLocal * N_CLASSES + k], acc[k]);
    __syncthreads();
    for (int e = tid; e < SAMPLES_PB * N_CLASSES; e += BLOCK) {
        int s = e / N_CLASSES, k = e - s * N_CLASSES;
        atomicAdd(&out[(size_t)(sample0 + s) * N_CLASSES + k], LR * sums[e]);
    }
}

extern "C" void kernel_launch(void* const* d_in, const int* in_sizes, int n_in,
                              void* d_out, int out_size, void* d_ws, size_t ws_size,
                              hipStream_t stream) {
    const float* x          = (const float*)d_in[0];
    const int*   features   = (const int*)d_in[1];
    const float* thresholds = (const float*)d_in[2];
    const float* leafvals   = (const float*)d_in[3];
    const float* init_out   = (const float*)d_in[4];
    float*       out        = (float*)d_out;

    {
        int n = BATCH * N_CLASSES;
        out_init_kernel<<<(n + 255) / 256, 256, 0, stream>>>(init_out, out);
    }

    dim3 grid(BATCH / SAMPLES_PB, TSPLIT);  // 1024 x 2

    if (ws_size >= WS_NODES_BYTES + WS_LEAVES_BYTES) {
        int2*  pn = (int2*)d_ws;
        float* pl = (float*)((char*)d_ws + WS_NODES_BYTES);
        int n = N_TREES * 64;
        pack_kernel<<<(n + 255) / 256, 256, 0, stream>>>(features, thresholds,
                                                         leafvals, pn, pl);
        gbt_eval<<<grid, BLOCK, 0, stream>>>(x, pn, pl, out);
    } else {
        gbt_eval_global<<<grid, BLOCK, 0, stream>>>(x, features, thresholds,
                                                    leafvals, out);
    }
}